// Round 8
// baseline (5050.444 us; speedup 1.0000x reference)
//
#include <hip/hip_runtime.h>
#include <hip/hip_bf16.h>
#include <stdint.h>

typedef __attribute__((ext_vector_type(8))) short s16x8;
typedef __attribute__((ext_vector_type(4))) float f32x4;
typedef unsigned short u16;

__device__ __forceinline__ float bf2f(u16 h){
  unsigned u = ((unsigned)h)<<16; float f; __builtin_memcpy(&f,&u,4); return f;
}
__device__ __forceinline__ u16 f2bf(float f){
  unsigned u; __builtin_memcpy(&u,&f,4);
  u = (u + 0x7FFFu + ((u>>16)&1u))>>16; return (u16)u;
}
__device__ __forceinline__ float fsig(float x){
  return __builtin_amdgcn_rcpf(1.f + __expf(-x));
}
__device__ __forceinline__ float ftanh(float x){
  float e = __expf(2.f*x);
  return 1.f - 2.f*__builtin_amdgcn_rcpf(e+1.f);
}
#define MFMA16(a,b,c) __builtin_amdgcn_mfma_f32_16x16x32_bf16(a,b,c,0,0,0)

// ---------------- f32 -> bf16 convert ----------------
__global__ __launch_bounds__(256) void cvt_k(const float* __restrict__ src, u16* __restrict__ dst, int n4){
  int i = blockIdx.x*256 + threadIdx.x;
  if (i >= n4) return;
  float4 v = ((const float4*)src)[i];
  ushort4 o; o.x=f2bf(v.x); o.y=f2bf(v.y); o.z=f2bf(v.z); o.w=f2bf(v.w);
  ((ushort4*)dst)[i] = o;
}

// ---------------- weight pack into MFMA B-fragment layout ----------------
struct PackJobs {
  const float* src[12];
  int ld[12];
  int NT[12];
  int end[12];
};

__global__ __launch_bounds__(256) void pack_k(PackJobs pj, u16* __restrict__ dst){
  int idx = blockIdx.x*256 + threadIdx.x;
  int jb = 0;
  while (idx >= pj.end[jb]) jb++;
  int start = (jb==0)?0:pj.end[jb-1];
  int local = idx - start;
  int j = local & 7;
  int l = (local>>3) & 63;
  int r2 = local>>9;
  int NT = pj.NT[jb];
  int nt = r2 % NT;
  int ki = r2 / NT;
  int krow = ki*32 + ((l>>4)<<3) + j;
  int col  = nt*16 + (l&15);
  dst[idx] = f2bf(pj.src[jb][(size_t)krow*pj.ld[jb] + col]);
}

// ---------------- generic MFMA GEMM (pre-loop only) ----------------
struct GJob {
  const void* A; int lda;
  const u16* Bp;
  void* C; int ldc;
  void* C2;
  const float* bias; int bstride;
  int NG; int KI; int NT; int waves;
};

template<int MTW, int EPI, bool BIAS, bool AF32>
__global__ __launch_bounds__(256) void gemm_k(GJob j0, GJob j1, int blocks0){
  bool first = ((int)blockIdx.x) < blocks0;
  GJob j = first ? j0 : j1;
  int bid = first ? (int)blockIdx.x : ((int)blockIdx.x - blocks0);
  int wid = bid*4 + ((int)threadIdx.x >> 6);
  if (wid >= j.waves) return;
  int lane = (int)threadIdx.x & 63;
  int r = lane & 15, g = lane >> 4;
  int mtg = wid / j.NG;
  int ng  = wid - mtg*j.NG;
  int arow = mtg*MTW*16 + r;
  f32x4 acc[MTW][8] = {};
  for (int ki=0; ki<j.KI; ++ki){
    s16x8 a[MTW];
    #pragma unroll
    for (int m=0;m<MTW;m++){
      if constexpr (AF32){
        const float* ap = (const float*)j.A + (size_t)(arow + m*16)*j.lda + g*8 + ki*32;
        float4 v0 = *(const float4*)ap;
        float4 v1 = *(const float4*)(ap+4);
        s16x8 t;
        t[0]=(short)f2bf(v0.x); t[1]=(short)f2bf(v0.y); t[2]=(short)f2bf(v0.z); t[3]=(short)f2bf(v0.w);
        t[4]=(short)f2bf(v1.x); t[5]=(short)f2bf(v1.y); t[6]=(short)f2bf(v1.z); t[7]=(short)f2bf(v1.w);
        a[m] = t;
      } else {
        const u16* ap = (const u16*)j.A + (size_t)(arow + m*16)*j.lda + g*8 + ki*32;
        a[m] = *(const s16x8*)ap;
      }
    }
    const u16* bp = j.Bp + (((size_t)ki*j.NT + ng*8)*64 + lane)*8;
    #pragma unroll
    for (int n=0;n<8;n++){
      s16x8 b = *(const s16x8*)(bp + n*512);
      #pragma unroll
      for (int m=0;m<MTW;m++){
        acc[m][n] = MFMA16(a[m], b, acc[m][n]);
      }
    }
  }
  #pragma unroll
  for (int m=0;m<MTW;m++){
    #pragma unroll
    for (int n=0;n<8;n++){
      #pragma unroll
      for (int q2=0;q2<4;q2++){
        int row = mtg*MTW*16 + m*16 + g*4 + q2;
        int col = (ng*8+n)*16 + r;
        float v = acc[m][n][q2];
        if (BIAS) v += j.bias[(size_t)row*j.bstride + col];
        if constexpr (EPI==3){
          u16 hb = f2bf(tanhf(v));
          if (row < 64) ((u16*)j.C)[(size_t)row*1152 + 768 + col] = hb;
          else          ((u16*)j.C2)[(size_t)(row-64)*768 + 384 + col] = hb;
        } else if constexpr (EPI==1){
          ((u16*)j.C)[(size_t)row*j.ldc + col] = f2bf(v);
        } else {
          ((float*)j.C)[(size_t)row*j.ldc + col] = v;
        }
      }
    }
  }
}

// ---------------- persistent megakernel: 32 steps, 4 phases, grid barrier ----------------
struct MegaA {
  const float* we;
  const u16* pk;
  const void* eh;          // ehb (bf16) or eh (f32)
  const u16* emb0b;
  const float* preemb;
  float* qws;
  u16 *xc0a, *xc0b, *xc1a, *xc1b, *xpre;
  const u16 *Bs0, *Bg0, *Bs1, *Bg1, *Bpre, *Bq;
  const float *bi0, *bh0, *bi1, *bh1;
  float *outst, *outh0, *outh1, *outpre;
  int* bar;                // [0]=cnt, [1]=gen
};

__device__ __forceinline__ void gridbar(int* cnt, int* gen){
  __syncthreads();
  if (threadIdx.x == 0){
    __threadfence();                       // publish this block's writes
    int g = atomicAdd(gen, 0);
    int old = atomicAdd(cnt, 1);
    if (old == 63){
      atomicExch(cnt, 0);
      __threadfence();                     // order reset before gen bump
      atomicAdd(gen, 1);
    } else {
      while (atomicAdd(gen, 0) == g) __builtin_amdgcn_s_sleep(2);
    }
    __threadfence();                       // acquire: invalidate stale caches
  }
  __syncthreads();
}

template<bool EHB>
__global__ __launch_bounds__(512) void mega_k(MegaA a){
  __shared__ float qls[384];
  __shared__ float wls[384];
  __shared__ float al[512];
  __shared__ float red[16];
  __shared__ float part[4][96][8];
  int blk = blockIdx.x, tid = threadIdx.x;
  int* cnt = a.bar; int* gen = a.bar + 1;

  for (int t=0;t<32;t++){
    u16* xc0cur = (t&1) ? a.xc0b : a.xc0a;
    u16* xc0nxt = (t&1) ? a.xc0a : a.xc0b;
    u16* xc1cur = (t&1) ? a.xc1b : a.xc1a;
    u16* xc1nxt = (t&1) ? a.xc1a : a.xc1b;

    // ======== phase 1: attention (all 64 blocks, b = blk) ========
    {
      int b = blk;
      if (tid < 384){ qls[tid]=a.qws[b*384+tid]; wls[tid]=a.we[tid]; }
      __syncthreads();
      const u16* p0 = a.pk + ((size_t)b*512 + tid)*384;
      float s0 = 0.f;
      #pragma unroll 4
      for (int u=0;u<384;u+=8){
        s16x8 v0 = *(const s16x8*)(p0+u);
        #pragma unroll
        for (int v=0;v<8;v++){
          s0 += ftanh(qls[u+v] + bf2f((u16)v0[v]))*wls[u+v];
        }
      }
      float m = s0;
      #pragma unroll
      for (int o=32;o>=1;o>>=1) m = fmaxf(m, __shfl_xor(m, o));
      int w = tid>>6;
      if ((tid&63)==0) red[w] = m;
      __syncthreads();
      m = red[0];
      #pragma unroll
      for (int i=1;i<8;i++) m = fmaxf(m, red[i]);
      float e0 = __expf(s0-m);
      al[tid] = e0;
      float sum = e0;
      #pragma unroll
      for (int o=32;o>=1;o>>=1) sum += __shfl_xor(sum, o);
      if ((tid&63)==0) red[8+w] = sum;
      __syncthreads();
      float tot = red[8];
      #pragma unroll
      for (int i=1;i<8;i++) tot += red[8+i];
      float rs = 1.f/tot;
      if (tid < 384){
        int cg = tid % 96, sc = tid / 96;
        float acc[8] = {0.f,0.f,0.f,0.f,0.f,0.f,0.f,0.f};
        const float* alp = &al[sc*128];
        if (EHB){
          const u16* ep = (const u16*)a.eh + (size_t)b*393216 + (size_t)sc*128*768 + cg*8;
          #pragma unroll 8
          for (int i=0;i<128;i++){
            float wv = alp[i];
            s16x8 v = *(const s16x8*)(ep + (size_t)i*768);
            #pragma unroll
            for (int jj=0;jj<8;jj++) acc[jj] += wv*bf2f((u16)v[jj]);
          }
        } else {
          const float* ep = (const float*)a.eh + (size_t)b*393216 + (size_t)sc*128*768 + cg*8;
          #pragma unroll 8
          for (int i=0;i<128;i++){
            float wv = alp[i];
            float4 v0 = *(const float4*)(ep + (size_t)i*768);
            float4 v1 = *(const float4*)(ep + (size_t)i*768 + 4);
            acc[0]+=wv*v0.x; acc[1]+=wv*v0.y; acc[2]+=wv*v0.z; acc[3]+=wv*v0.w;
            acc[4]+=wv*v1.x; acc[5]+=wv*v1.y; acc[6]+=wv*v1.z; acc[7]+=wv*v1.w;
          }
        }
        #pragma unroll
        for (int jj=0;jj<8;jj++) part[sc][cg][jj] = acc[jj];
      }
      __syncthreads();
      for (int c = tid; c < 768; c += 512){
        float v = part[0][c>>3][c&7] + part[1][c>>3][c&7] + part[2][c>>3][c&7] + part[3][c>>3][c&7];
        u16 cb = f2bf(v*rs);
        xc0cur[(size_t)b*1152 + c] = cb;
        a.xpre[(size_t)b*1152 + 384 + c] = cb;
      }
    }
    gridbar(cnt, gen);

    // ======== phase 2: GRU layer 0 (blocks 0..23, tid<256) ========
    if (blk < 24 && tid < 256){
      int bc = blk;
      int w = tid >> 6, lane = tid & 63, r = lane & 15, g = lane >> 4;
      const u16* Arow = xc0cur + (size_t)(w*16 + r)*1152 + g*8;
      f32x4 aR={},aZ={},aN={},aG={};
      #pragma unroll 4
      for (int ki=0;ki<36;ki++){
        s16x8 aa = *(const s16x8*)(Arow + ki*32);
        const u16* bp = a.Bs0 + (((size_t)ki*72)*64 + lane)*8 + (size_t)bc*512;
        aR = MFMA16(aa, *(const s16x8*)(bp), aR);
        aZ = MFMA16(aa, *(const s16x8*)(bp + 24*512), aZ);
        aN = MFMA16(aa, *(const s16x8*)(bp + 48*512), aN);
      }
      #pragma unroll 4
      for (int ki=0;ki<12;ki++){
        s16x8 aa = *(const s16x8*)(Arow + 768 + ki*32);
        aG = MFMA16(aa, *(const s16x8*)(a.Bg0 + (((size_t)ki*24 + bc)*64 + lane)*8), aG);
      }
      int col = bc*16 + r;
      float biR=a.bi0[col], biZ=a.bi0[384+col], biN=a.bi0[768+col];
      float bhR=a.bh0[col], bhZ=a.bh0[384+col], bhN=a.bh0[768+col];
      #pragma unroll
      for (int q=0;q<4;q++){
        int row = w*16 + g*4 + q;
        const u16* e = a.emb0b + ((size_t)row*32 + t)*1152;
        float rr = fsig(bf2f(e[col]) + biR + aR[q] + bhR);
        float zz = fsig(bf2f(e[384+col]) + biZ + aZ[q] + bhZ);
        float nn = ftanh(bf2f(e[768+col]) + biN + (aN[q]-aG[q]) + rr*(aG[q]+bhN));
        float hp = bf2f(xc0cur[(size_t)row*1152 + 768 + col]);
        float h = (1.f-zz)*nn + zz*hp;
        u16 hb = f2bf(h);
        xc0nxt[(size_t)row*1152 + 768 + col] = hb;
        xc1cur[(size_t)row*768 + col] = hb;
        if (t==31) a.outh0[(size_t)row*384 + col] = h;
      }
    }
    gridbar(cnt, gen);

    // ======== phase 3: GRU layer 1 ========
    if (blk < 24 && tid < 256){
      int bc = blk;
      int w = tid >> 6, lane = tid & 63, r = lane & 15, g = lane >> 4;
      const u16* Arow = xc1cur + (size_t)(w*16 + r)*768 + g*8;
      f32x4 aR={},aZ={},aN={},aG={};
      #pragma unroll 4
      for (int ki=0;ki<24;ki++){
        s16x8 aa = *(const s16x8*)(Arow + ki*32);
        const u16* bp = a.Bs1 + (((size_t)ki*72)*64 + lane)*8 + (size_t)bc*512;
        aR = MFMA16(aa, *(const s16x8*)(bp), aR);
        aZ = MFMA16(aa, *(const s16x8*)(bp + 24*512), aZ);
        aN = MFMA16(aa, *(const s16x8*)(bp + 48*512), aN);
      }
      #pragma unroll 4
      for (int ki=0;ki<12;ki++){
        s16x8 aa = *(const s16x8*)(Arow + 384 + ki*32);
        aG = MFMA16(aa, *(const s16x8*)(a.Bg1 + (((size_t)ki*24 + bc)*64 + lane)*8), aG);
      }
      int col = bc*16 + r;
      float biR=a.bi1[col], biZ=a.bi1[384+col], biN=a.bi1[768+col];
      float bhR=a.bh1[col], bhZ=a.bh1[384+col], bhN=a.bh1[768+col];
      #pragma unroll
      for (int q=0;q<4;q++){
        int row = w*16 + g*4 + q;
        float rr = fsig(aR[q] + biR + bhR);
        float zz = fsig(aZ[q] + biZ + bhZ);
        float nn = ftanh(aN[q] + biN - aG[q] + rr*(aG[q]+bhN));
        float hp = bf2f(xc1cur[(size_t)row*768 + 384 + col]);
        float h = (1.f-zz)*nn + zz*hp;
        u16 hb = f2bf(h);
        xc1nxt[(size_t)row*768 + 384 + col] = hb;
        a.xpre[(size_t)row*1152 + col] = hb;
        a.outst[((size_t)row*32 + t)*384 + col] = h;
        if (t==31) a.outh1[(size_t)row*384 + col] = h;
      }
    }
    gridbar(cnt, gen);

    // ======== phase 4: pre-output + q ========
    if (blk < 24 && tid < 256){
      int bc = blk;
      int w = tid >> 6, lane = tid & 63, r = lane & 15, g = lane >> 4;
      const u16* Arow = a.xpre + (size_t)(w*16 + r)*1152 + g*8;
      f32x4 ap={}, aq={};
      #pragma unroll 4
      for (int ki=0;ki<36;ki++){
        s16x8 aa = *(const s16x8*)(Arow + ki*32);
        ap = MFMA16(aa, *(const s16x8*)(a.Bpre + (((size_t)ki*24 + bc)*64 + lane)*8), ap);
      }
      #pragma unroll 4
      for (int ki=0;ki<12;ki++){
        s16x8 aa = *(const s16x8*)(Arow + ki*32);
        aq = MFMA16(aa, *(const s16x8*)(a.Bq + (((size_t)ki*24 + bc)*64 + lane)*8), aq);
      }
      int col = bc*16 + r;
      #pragma unroll
      for (int q=0;q<4;q++){
        int row = w*16 + g*4 + q;
        a.outpre[((size_t)row*32 + t)*384 + col] = ap[q] + a.preemb[((size_t)row*32 + t)*384 + col];
        a.qws[(size_t)row*384 + col] = aq[q];
      }
    }
    gridbar(cnt, gen);
  }
}

extern "C" void kernel_launch(void* const* d_in, const int* in_sizes, int n_in,
                              void* d_out, int out_size, void* d_ws, size_t ws_size,
                              hipStream_t stream){
  (void)in_sizes; (void)n_in; (void)out_size;
  const float* trg  = (const float*)d_in[0];
  const float* eh   = (const float*)d_in[1];
  const float* ef   = (const float*)d_in[2];
  const float* wkey = (const float*)d_in[4];
  const float* wq   = (const float*)d_in[5];
  const float* wen  = (const float*)d_in[6];
  const float* wbr  = (const float*)d_in[7];
  const float* bbr  = (const float*)d_in[8];
  const float* wih0 = (const float*)d_in[9];
  const float* whh0 = (const float*)d_in[10];
  const float* bih0 = (const float*)d_in[11];
  const float* bhh0 = (const float*)d_in[12];
  const float* wih1 = (const float*)d_in[13];
  const float* whh1 = (const float*)d_in[14];
  const float* bih1 = (const float*)d_in[15];
  const float* bhh1 = (const float*)d_in[16];
  const float* wpre = (const float*)d_in[17];

  float* out = (float*)d_out;
  float* outst = out;
  float* outh  = out + 786432;
  float* outpre= out + 835584;

  char* ws = (char*)d_ws;
  u16*   pk    = (u16*)(ws + 0);
  u16*   packs = (u16*)(ws + 25165824);
  u16*   emb0b = (u16*)(ws + 34897920);
  float* preemb= (float*)(ws + 39616512);
  float* qws   = (float*)(ws + 42762240);
  u16*   xc0a  = (u16*)(ws + 42860544);
  u16*   xc0b  = (u16*)(ws + 43008000);
  u16*   xc1a  = (u16*)(ws + 43155456);
  u16*   xc1b  = (u16*)(ws + 43253760);
  u16*   xpre  = (u16*)(ws + 43352064);
  int*   bar   = (int*)(ws + 43499520);    // 1 KB barrier space
  const size_t EHB_OFF = 43500544;
  const size_t EHB_BYTES = 50331648;
  bool use_ehb = (ws_size >= EHB_OFF + EHB_BYTES);
  u16* ehb = (u16*)(ws + EHB_OFF);

  u16* wkeyP  = packs;
  u16* wcat0P = packs + 294912;
  u16* whh0nP = packs + 1622016;
  u16* wcat1P = packs + 1769472;
  u16* whh1nP = packs + 2654208;
  u16* wih0eP = packs + 2801664;
  u16* wpreeP = packs + 3686400;
  u16* wprerP = packs + 3981312;
  u16* wqP    = packs + 4423680;
  u16* wbrP   = packs + 4571136;

  hipMemsetAsync(bar, 0, 1024, stream);
  if (use_ehb) cvt_k<<<24576, 256, 0, stream>>>(eh, ehb, 6291456);

  PackJobs pj;
  const float* srcs[12] = {wkey, wih0 + 768*1152, whh0, whh0 + 768, wih1,
                           whh1, whh1 + 768, wih0, wpre, wpre + 768*384, wq, wbr};
  int ldsv[12] = {384,1152,1152,1152,1152,1152,1152,1152,384,384,384,384};
  int nts[12]  = {24,  72,  72,  24,  72,  72,  24,  72,  24, 24, 24, 24};
  int kis[12]  = {24,  24,  12,  12,  12,  12,  12,  24,  24, 36, 12, 24};
  int cum=0;
  for (int k=0;k<12;k++){ pj.src[k]=srcs[k]; pj.ld[k]=ldsv[k]; pj.NT[k]=nts[k];
                          cum += kis[k]*nts[k]*512; pj.end[k]=cum; }
  pack_k<<<cum/256, 256, 0, stream>>>(pj, packs);

  auto mk = [](const void* A, int lda, const u16* Bp, void* C, int ldc,
               const float* bias, int bstride, int NG, int KI, int waves){
    GJob j; j.A=A; j.lda=lda; j.Bp=Bp; j.C=C; j.ldc=ldc; j.C2=nullptr;
    j.bias=bias; j.bstride=bstride;
    j.NG=NG; j.KI=KI; j.NT=NG*8; j.waves=waves; return j;
  };

  // bridge
  GJob jBR = mk(ef, 768, wbrP, xc0a, 1152, bbr, 0, 3, 24, 12);
  jBR.C2 = xc1a;
  gemm_k<2,3,true,true><<<3, 256, 0, stream>>>(jBR, jBR, 3);

  // q0
  GJob jQ0 = mk(xc1a + 384, 768, wqP, qws, 384, nullptr, 0, 3, 12, 12);
  gemm_k<1,0,false,false><<<3, 256, 0, stream>>>(jQ0, jQ0, 3);

  // proj_key
  if (use_ehb){
    GJob jPK = mk(ehb, 768, wkeyP, pk, 384, nullptr, 0, 3, 24, 3072);
    gemm_k<2,1,false,false><<<768, 256, 0, stream>>>(jPK, jPK, 768);
  } else {
    GJob jPK = mk(eh, 768, wkeyP, pk, 384, nullptr, 0, 3, 24, 3072);
    gemm_k<2,1,false,true><<<768, 256, 0, stream>>>(jPK, jPK, 768);
  }

  // embed precomputes
  GJob jE0 = mk(trg, 768, wih0eP, emb0b, 1152, nullptr, 0, 9, 24, 576);
  gemm_k<2,1,false,true><<<144, 256, 0, stream>>>(jE0, jE0, 144);
  GJob jE1 = mk(trg, 768, wpreeP, preemb, 384, nullptr, 0, 3, 24, 192);
  gemm_k<2,0,false,true><<<48, 256, 0, stream>>>(jE1, jE1, 48);

  // persistent 32-step loop
  MegaA a;
  a.we = wen; a.pk = pk; a.eh = use_ehb ? (const void*)ehb : (const void*)eh;
  a.emb0b = emb0b; a.preemb = preemb; a.qws = qws;
  a.xc0a = xc0a; a.xc0b = xc0b; a.xc1a = xc1a; a.xc1b = xc1b; a.xpre = xpre;
  a.Bs0 = wcat0P; a.Bg0 = whh0nP; a.Bs1 = wcat1P; a.Bg1 = whh1nP;
  a.Bpre = wprerP; a.Bq = wqP;
  a.bi0 = bih0; a.bh0 = bhh0; a.bi1 = bih1; a.bh1 = bhh1;
  a.outst = outst; a.outh0 = outh; a.outh1 = outh + 24576; a.outpre = outpre;
  a.bar = bar;
  if (use_ehb) mega_k<true><<<64, 512, 0, stream>>>(a);
  else         mega_k<false><<<64, 512, 0, stream>>>(a);
}

// Round 9
// 2334.464 us; speedup vs baseline: 2.1634x; 2.1634x over previous
//
#include <hip/hip_runtime.h>
#include <hip/hip_bf16.h>
#include <stdint.h>

typedef __attribute__((ext_vector_type(8))) short s16x8;
typedef __attribute__((ext_vector_type(4))) float f32x4;
typedef unsigned short u16;

__device__ __forceinline__ float bf2f(u16 h){
  unsigned u = ((unsigned)h)<<16; float f; __builtin_memcpy(&f,&u,4); return f;
}
__device__ __forceinline__ u16 f2bf(float f){
  unsigned u; __builtin_memcpy(&u,&f,4);
  u = (u + 0x7FFFu + ((u>>16)&1u))>>16; return (u16)u;
}
__device__ __forceinline__ float fsig(float x){
  return __builtin_amdgcn_rcpf(1.f + __expf(-x));
}
__device__ __forceinline__ float ftanh(float x){
  float e = __expf(2.f*x);
  return 1.f - 2.f*__builtin_amdgcn_rcpf(e+1.f);
}
#define MFMA16(a,b,c) __builtin_amdgcn_mfma_f32_16x16x32_bf16(a,b,c,0,0,0)

// ---------------- f32 -> bf16 convert ----------------
__global__ __launch_bounds__(256) void cvt_k(const float* __restrict__ src, u16* __restrict__ dst, int n4){
  int i = blockIdx.x*256 + threadIdx.x;
  if (i >= n4) return;
  float4 v = ((const float4*)src)[i];
  ushort4 o; o.x=f2bf(v.x); o.y=f2bf(v.y); o.z=f2bf(v.z); o.w=f2bf(v.w);
  ((ushort4*)dst)[i] = o;
}

// ---------------- weight pack into MFMA B-fragment layout ----------------
struct PackJobs {
  const float* src[12];
  int ld[12];
  int NT[12];
  int end[12];
};

__global__ __launch_bounds__(256) void pack_k(PackJobs pj, u16* __restrict__ dst){
  int idx = blockIdx.x*256 + threadIdx.x;
  int jb = 0;
  while (idx >= pj.end[jb]) jb++;
  int start = (jb==0)?0:pj.end[jb-1];
  int local = idx - start;
  int j = local & 7;
  int l = (local>>3) & 63;
  int r2 = local>>9;
  int NT = pj.NT[jb];
  int nt = r2 % NT;
  int ki = r2 / NT;
  int krow = ki*32 + ((l>>4)<<3) + j;
  int col  = nt*16 + (l&15);
  dst[idx] = f2bf(pj.src[jb][(size_t)krow*pj.ld[jb] + col]);
}

// ---------------- generic MFMA GEMM (pre-loop only) ----------------
struct GJob {
  const void* A; int lda;
  const u16* Bp;
  void* C; int ldc;
  void* C2;
  const float* bias; int bstride;
  int NG; int KI; int NT; int waves;
};

template<int MTW, int EPI, bool BIAS, bool AF32>
__global__ __launch_bounds__(256) void gemm_k(GJob j0, GJob j1, int blocks0){
  bool first = ((int)blockIdx.x) < blocks0;
  GJob j = first ? j0 : j1;
  int bid = first ? (int)blockIdx.x : ((int)blockIdx.x - blocks0);
  int wid = bid*4 + ((int)threadIdx.x >> 6);
  if (wid >= j.waves) return;
  int lane = (int)threadIdx.x & 63;
  int r = lane & 15, g = lane >> 4;
  int mtg = wid / j.NG;
  int ng  = wid - mtg*j.NG;
  int arow = mtg*MTW*16 + r;
  f32x4 acc[MTW][8] = {};
  for (int ki=0; ki<j.KI; ++ki){
    s16x8 a[MTW];
    #pragma unroll
    for (int m=0;m<MTW;m++){
      if constexpr (AF32){
        const float* ap = (const float*)j.A + (size_t)(arow + m*16)*j.lda + g*8 + ki*32;
        float4 v0 = *(const float4*)ap;
        float4 v1 = *(const float4*)(ap+4);
        s16x8 t;
        t[0]=(short)f2bf(v0.x); t[1]=(short)f2bf(v0.y); t[2]=(short)f2bf(v0.z); t[3]=(short)f2bf(v0.w);
        t[4]=(short)f2bf(v1.x); t[5]=(short)f2bf(v1.y); t[6]=(short)f2bf(v1.z); t[7]=(short)f2bf(v1.w);
        a[m] = t;
      } else {
        const u16* ap = (const u16*)j.A + (size_t)(arow + m*16)*j.lda + g*8 + ki*32;
        a[m] = *(const s16x8*)ap;
      }
    }
    const u16* bp = j.Bp + (((size_t)ki*j.NT + ng*8)*64 + lane)*8;
    #pragma unroll
    for (int n=0;n<8;n++){
      s16x8 b = *(const s16x8*)(bp + n*512);
      #pragma unroll
      for (int m=0;m<MTW;m++){
        acc[m][n] = MFMA16(a[m], b, acc[m][n]);
      }
    }
  }
  #pragma unroll
  for (int m=0;m<MTW;m++){
    #pragma unroll
    for (int n=0;n<8;n++){
      #pragma unroll
      for (int q2=0;q2<4;q2++){
        int row = mtg*MTW*16 + m*16 + g*4 + q2;
        int col = (ng*8+n)*16 + r;
        float v = acc[m][n][q2];
        if (BIAS) v += j.bias[(size_t)row*j.bstride + col];
        if constexpr (EPI==3){
          u16 hb = f2bf(tanhf(v));
          if (row < 64) ((u16*)j.C)[(size_t)row*1152 + 768 + col] = hb;
          else          ((u16*)j.C2)[(size_t)(row-64)*768 + 384 + col] = hb;
        } else if constexpr (EPI==1){
          ((u16*)j.C)[(size_t)row*j.ldc + col] = f2bf(v);
        } else {
          ((float*)j.C)[(size_t)row*j.ldc + col] = v;
        }
      }
    }
  }
}

// ---------------- attention partial: 256 blocks = 64 b x 4 s-chunks of 128 ----------------
// scores(128 rows) + online softmax + partial ctx -> ctxp[b][sc][768], ml[b][sc]={m,l}
template<bool EHB>
__global__ __launch_bounds__(512) void attnpart_k(const float* __restrict__ qin,
      const float* __restrict__ we, const u16* __restrict__ pk, const void* __restrict__ eh,
      float* __restrict__ ctxp, float* __restrict__ ml){
  __shared__ float qls[384];
  __shared__ float wls[384];
  __shared__ float sl[128];
  __shared__ float al[128];
  __shared__ float red[16];
  int b = (int)blockIdx.x >> 2, sc = (int)blockIdx.x & 3;
  int tid = threadIdx.x;
  if (tid < 384){ qls[tid]=qin[b*384+tid]; wls[tid]=we[tid]; }
  __syncthreads();
  // ---- scores: 4 lanes per row (ch = tid&3), cols ch*8 + k*32 + j ----
  {
    int rl = tid >> 2, ch = tid & 3;
    const u16* p0 = pk + ((size_t)(b*512 + sc*128 + rl))*384 + ch*8;
    float acc = 0.f;
    #pragma unroll 4
    for (int k=0;k<12;k++){
      s16x8 v = *(const s16x8*)(p0 + k*32);
      int cb = ch*8 + k*32;
      #pragma unroll
      for (int j=0;j<8;j++){
        acc += ftanh(qls[cb+j] + bf2f((u16)v[j]))*wls[cb+j];
      }
    }
    acc += __shfl_xor(acc, 1);
    acc += __shfl_xor(acc, 2);
    if (ch==0) sl[rl] = acc;
  }
  __syncthreads();
  // ---- partial softmax over 128 rows ----
  float x = sl[tid & 127];
  float m = x;
  #pragma unroll
  for (int o=32;o>=1;o>>=1) m = fmaxf(m, __shfl_xor(m, o));
  int w = tid>>6;
  if ((tid&63)==0) red[w] = m;
  __syncthreads();
  m = red[0];
  #pragma unroll
  for (int i=1;i<8;i++) m = fmaxf(m, red[i]);
  float e = (tid < 128) ? __expf(sl[tid]-m) : 0.f;
  if (tid < 128) al[tid] = e;
  float sum = e;
  #pragma unroll
  for (int o=32;o>=1;o>>=1) sum += __shfl_xor(sum, o);
  if ((tid&63)==0) red[8+w] = sum;
  __syncthreads();
  if (tid == 0){
    float l = red[8]+red[9];   // only waves 0,1 have tid<128
    ml[(b*4+sc)*2] = m;
    ml[(b*4+sc)*2+1] = l;
  }
  // ---- partial ctx: threads 0..383, col pair c=2*tid ----
  if (tid < 384){
    int c = tid*2;
    float a0=0.f, a1=0.f;
    if (EHB){
      const u16* ep = (const u16*)eh + (size_t)b*393216 + (size_t)sc*128*768 + c;
      for (int i=0;i<128;i++){
        float wv = al[i];
        unsigned pv = *(const unsigned*)(ep + (size_t)i*768);
        a0 += wv*bf2f((u16)(pv & 0xFFFF));
        a1 += wv*bf2f((u16)(pv >> 16));
      }
    } else {
      const float* ep = (const float*)eh + (size_t)b*393216 + (size_t)sc*128*768 + c;
      for (int i=0;i<128;i++){
        float wv = al[i];
        float2 pv = *(const float2*)(ep + (size_t)i*768);
        a0 += wv*pv.x; a1 += wv*pv.y;
      }
    }
    *(float2*)&ctxp[((size_t)(b*4+sc))*768 + c] = make_float2(a0, a1);
  }
}

// ---------------- ctx reduce: combine 4 partials, write bf16 ctx ----------------
__global__ __launch_bounds__(384) void ctxred_k(const float* __restrict__ ctxp,
      const float* __restrict__ ml, u16* __restrict__ xc0cur, u16* __restrict__ xpre){
  int b = blockIdx.x, tid = threadIdx.x;
  float m0=ml[b*8], l0=ml[b*8+1], m1=ml[b*8+2], l1=ml[b*8+3];
  float m2=ml[b*8+4], l2=ml[b*8+5], m3=ml[b*8+6], l3=ml[b*8+7];
  float M = fmaxf(fmaxf(m0,m1), fmaxf(m2,m3));
  float c0=__expf(m0-M), c1=__expf(m1-M), c2=__expf(m2-M), c3=__expf(m3-M);
  float rs = 1.f/(l0*c0 + l1*c1 + l2*c2 + l3*c3);
  int c = tid*2;
  float2 v0 = *(const float2*)&ctxp[((size_t)b*4+0)*768 + c];
  float2 v1 = *(const float2*)&ctxp[((size_t)b*4+1)*768 + c];
  float2 v2 = *(const float2*)&ctxp[((size_t)b*4+2)*768 + c];
  float2 v3 = *(const float2*)&ctxp[((size_t)b*4+3)*768 + c];
  float r0 = (v0.x*c0 + v1.x*c1 + v2.x*c2 + v3.x*c3)*rs;
  float r1 = (v0.y*c0 + v1.y*c1 + v2.y*c2 + v3.y*c3)*rs;
  u16 h0 = f2bf(r0), h1 = f2bf(r1);
  xc0cur[(size_t)b*1152 + c] = h0;   xc0cur[(size_t)b*1152 + c + 1] = h1;
  xpre[(size_t)b*1152 + 384 + c] = h0; xpre[(size_t)b*1152 + 384 + c + 1] = h1;
}

// ---------------- GRU layer 0 ----------------
__global__ __launch_bounds__(256) void gru0_k(const u16* __restrict__ xc0cur, u16* __restrict__ xc0next,
        u16* __restrict__ xc1cur, const u16* __restrict__ Bs, const u16* __restrict__ Bg,
        const u16* __restrict__ emb, const float* __restrict__ bi, const float* __restrict__ bh,
        float* __restrict__ outh0, int t){
  int bc = blockIdx.x;
  int w = (int)threadIdx.x >> 6;
  int lane = (int)threadIdx.x & 63;
  int r = lane & 15, g = lane >> 4;
  const u16* Arow = xc0cur + (size_t)(w*16 + r)*1152 + g*8;
  f32x4 aR={},aZ={},aN={},aG={};
  #pragma unroll 4
  for (int ki=0;ki<36;ki++){
    s16x8 a = *(const s16x8*)(Arow + ki*32);
    const u16* bp = Bs + (((size_t)ki*72)*64 + lane)*8 + (size_t)bc*512;
    aR = MFMA16(a, *(const s16x8*)(bp), aR);
    aZ = MFMA16(a, *(const s16x8*)(bp + 24*512), aZ);
    aN = MFMA16(a, *(const s16x8*)(bp + 48*512), aN);
  }
  #pragma unroll 4
  for (int ki=0;ki<12;ki++){
    s16x8 a = *(const s16x8*)(Arow + 768 + ki*32);
    aG = MFMA16(a, *(const s16x8*)(Bg + (((size_t)ki*24 + bc)*64 + lane)*8), aG);
  }
  int col = bc*16 + r;
  float biR=bi[col], biZ=bi[384+col], biN=bi[768+col];
  float bhR=bh[col], bhZ=bh[384+col], bhN=bh[768+col];
  #pragma unroll
  for (int q=0;q<4;q++){
    int row = w*16 + g*4 + q;
    const u16* e = emb + ((size_t)row*32 + t)*1152;
    float rr = fsig(bf2f(e[col]) + biR + aR[q] + bhR);
    float zz = fsig(bf2f(e[384+col]) + biZ + aZ[q] + bhZ);
    float nn = ftanh(bf2f(e[768+col]) + biN + (aN[q]-aG[q]) + rr*(aG[q]+bhN));
    float hp = bf2f(xc0cur[(size_t)row*1152 + 768 + col]);
    float h = (1.f-zz)*nn + zz*hp;
    u16 hb = f2bf(h);
    xc0next[(size_t)row*1152 + 768 + col] = hb;
    xc1cur[(size_t)row*768 + col] = hb;
    if (t==31) outh0[(size_t)row*384 + col] = h;
  }
}

// ---------------- GRU layer 1 ----------------
__global__ __launch_bounds__(256) void gru1_k(const u16* __restrict__ xc1cur, u16* __restrict__ xc1next,
        u16* __restrict__ xpre, const u16* __restrict__ Bs, const u16* __restrict__ Bg,
        const float* __restrict__ bi, const float* __restrict__ bh,
        float* __restrict__ outst, float* __restrict__ outh1, int t){
  int bc = blockIdx.x;
  int w = (int)threadIdx.x >> 6;
  int lane = (int)threadIdx.x & 63;
  int r = lane & 15, g = lane >> 4;
  const u16* Arow = xc1cur + (size_t)(w*16 + r)*768 + g*8;
  f32x4 aR={},aZ={},aN={},aG={};
  #pragma unroll 4
  for (int ki=0;ki<24;ki++){
    s16x8 a = *(const s16x8*)(Arow + ki*32);
    const u16* bp = Bs + (((size_t)ki*72)*64 + lane)*8 + (size_t)bc*512;
    aR = MFMA16(a, *(const s16x8*)(bp), aR);
    aZ = MFMA16(a, *(const s16x8*)(bp + 24*512), aZ);
    aN = MFMA16(a, *(const s16x8*)(bp + 48*512), aN);
  }
  #pragma unroll 4
  for (int ki=0;ki<12;ki++){
    s16x8 a = *(const s16x8*)(Arow + 384 + ki*32);
    aG = MFMA16(a, *(const s16x8*)(Bg + (((size_t)ki*24 + bc)*64 + lane)*8), aG);
  }
  int col = bc*16 + r;
  float biR=bi[col], biZ=bi[384+col], biN=bi[768+col];
  float bhR=bh[col], bhZ=bh[384+col], bhN=bh[768+col];
  #pragma unroll
  for (int q=0;q<4;q++){
    int row = w*16 + g*4 + q;
    float rr = fsig(aR[q] + biR + bhR);
    float zz = fsig(aZ[q] + biZ + bhZ);
    float nn = ftanh(aN[q] + biN - aG[q] + rr*(aG[q]+bhN));
    float hp = bf2f(xc1cur[(size_t)row*768 + 384 + col]);
    float h = (1.f-zz)*nn + zz*hp;
    u16 hb = f2bf(h);
    xc1next[(size_t)row*768 + 384 + col] = hb;
    xpre[(size_t)row*1152 + col] = hb;
    outst[((size_t)row*32 + t)*384 + col] = h;
    if (t==31) outh1[(size_t)row*384 + col] = h;
  }
}

// ---------------- pre-output + q GEMMs ----------------
__global__ __launch_bounds__(256) void preq_k(const u16* __restrict__ xpre, const u16* __restrict__ Bpre,
        const u16* __restrict__ Bq, const float* __restrict__ preemb, float* __restrict__ outpre,
        float* __restrict__ qws, int t){
  int bc = blockIdx.x;
  int w = (int)threadIdx.x >> 6;
  int lane = (int)threadIdx.x & 63;
  int r = lane & 15, g = lane >> 4;
  const u16* Arow = xpre + (size_t)(w*16 + r)*1152 + g*8;
  f32x4 ap={}, aq={};
  #pragma unroll 4
  for (int ki=0;ki<36;ki++){
    s16x8 a = *(const s16x8*)(Arow + ki*32);
    ap = MFMA16(a, *(const s16x8*)(Bpre + (((size_t)ki*24 + bc)*64 + lane)*8), ap);
  }
  #pragma unroll 4
  for (int ki=0;ki<12;ki++){
    s16x8 a = *(const s16x8*)(Arow + ki*32);
    aq = MFMA16(a, *(const s16x8*)(Bq + (((size_t)ki*24 + bc)*64 + lane)*8), aq);
  }
  int col = bc*16 + r;
  #pragma unroll
  for (int q=0;q<4;q++){
    int row = w*16 + g*4 + q;
    outpre[((size_t)row*32 + t)*384 + col] = ap[q] + preemb[((size_t)row*32 + t)*384 + col];
    qws[(size_t)row*384 + col] = aq[q];
  }
}

extern "C" void kernel_launch(void* const* d_in, const int* in_sizes, int n_in,
                              void* d_out, int out_size, void* d_ws, size_t ws_size,
                              hipStream_t stream){
  (void)in_sizes; (void)n_in; (void)out_size;
  const float* trg  = (const float*)d_in[0];
  const float* eh   = (const float*)d_in[1];
  const float* ef   = (const float*)d_in[2];
  const float* wkey = (const float*)d_in[4];
  const float* wq   = (const float*)d_in[5];
  const float* wen  = (const float*)d_in[6];
  const float* wbr  = (const float*)d_in[7];
  const float* bbr  = (const float*)d_in[8];
  const float* wih0 = (const float*)d_in[9];
  const float* whh0 = (const float*)d_in[10];
  const float* bih0 = (const float*)d_in[11];
  const float* bhh0 = (const float*)d_in[12];
  const float* wih1 = (const float*)d_in[13];
  const float* whh1 = (const float*)d_in[14];
  const float* bih1 = (const float*)d_in[15];
  const float* bhh1 = (const float*)d_in[16];
  const float* wpre = (const float*)d_in[17];

  float* out = (float*)d_out;
  float* outst = out;
  float* outh  = out + 786432;
  float* outpre= out + 835584;

  char* ws = (char*)d_ws;
  u16*   pk    = (u16*)(ws + 0);
  u16*   packs = (u16*)(ws + 25165824);
  u16*   emb0b = (u16*)(ws + 34897920);
  float* preemb= (float*)(ws + 39616512);
  float* qws   = (float*)(ws + 42762240);
  u16*   xc0a  = (u16*)(ws + 42860544);
  u16*   xc0b  = (u16*)(ws + 43008000);
  u16*   xc1a  = (u16*)(ws + 43155456);
  u16*   xc1b  = (u16*)(ws + 43253760);
  u16*   xpre  = (u16*)(ws + 43352064);
  float* ctxp  = (float*)(ws + 43499520);   // [64][4][768] f32
  float* ml    = (float*)(ws + 44285952);   // [64][4][2] f32
  const size_t EHB_OFF = 44288000;
  const size_t EHB_BYTES = 50331648;
  bool use_ehb = (ws_size >= EHB_OFF + EHB_BYTES);
  u16* ehb = (u16*)(ws + EHB_OFF);

  u16* wkeyP  = packs;
  u16* wcat0P = packs + 294912;
  u16* whh0nP = packs + 1622016;
  u16* wcat1P = packs + 1769472;
  u16* whh1nP = packs + 2654208;
  u16* wih0eP = packs + 2801664;
  u16* wpreeP = packs + 3686400;
  u16* wprerP = packs + 3981312;
  u16* wqP    = packs + 4423680;
  u16* wbrP   = packs + 4571136;

  if (use_ehb) cvt_k<<<24576, 256, 0, stream>>>(eh, ehb, 6291456);

  PackJobs pj;
  const float* srcs[12] = {wkey, wih0 + 768*1152, whh0, whh0 + 768, wih1,
                           whh1, whh1 + 768, wih0, wpre, wpre + 768*384, wq, wbr};
  int ldsv[12] = {384,1152,1152,1152,1152,1152,1152,1152,384,384,384,384};
  int nts[12]  = {24,  72,  72,  24,  72,  72,  24,  72,  24, 24, 24, 24};
  int kis[12]  = {24,  24,  12,  12,  12,  12,  12,  24,  24, 36, 12, 24};
  int cum=0;
  for (int k=0;k<12;k++){ pj.src[k]=srcs[k]; pj.ld[k]=ldsv[k]; pj.NT[k]=nts[k];
                          cum += kis[k]*nts[k]*512; pj.end[k]=cum; }
  pack_k<<<cum/256, 256, 0, stream>>>(pj, packs);

  auto mk = [](const void* A, int lda, const u16* Bp, void* C, int ldc,
               const float* bias, int bstride, int NG, int KI, int waves){
    GJob j; j.A=A; j.lda=lda; j.Bp=Bp; j.C=C; j.ldc=ldc; j.C2=nullptr;
    j.bias=bias; j.bstride=bstride;
    j.NG=NG; j.KI=KI; j.NT=NG*8; j.waves=waves; return j;
  };

  // bridge
  GJob jBR = mk(ef, 768, wbrP, xc0a, 1152, bbr, 0, 3, 24, 12);
  jBR.C2 = xc1a;
  gemm_k<2,3,true,true><<<3, 256, 0, stream>>>(jBR, jBR, 3);

  // q0
  GJob jQ0 = mk(xc1a + 384, 768, wqP, qws, 384, nullptr, 0, 3, 12, 12);
  gemm_k<1,0,false,false><<<3, 256, 0, stream>>>(jQ0, jQ0, 3);

  // proj_key
  if (use_ehb){
    GJob jPK = mk(ehb, 768, wkeyP, pk, 384, nullptr, 0, 3, 24, 3072);
    gemm_k<2,1,false,false><<<768, 256, 0, stream>>>(jPK, jPK, 768);
  } else {
    GJob jPK = mk(eh, 768, wkeyP, pk, 384, nullptr, 0, 3, 24, 3072);
    gemm_k<2,1,false,true><<<768, 256, 0, stream>>>(jPK, jPK, 768);
  }

  // embed precomputes
  GJob jE0 = mk(trg, 768, wih0eP, emb0b, 1152, nullptr, 0, 9, 24, 576);
  gemm_k<2,1,false,true><<<144, 256, 0, stream>>>(jE0, jE0, 144);
  GJob jE1 = mk(trg, 768, wpreeP, preemb, 384, nullptr, 0, 3, 24, 192);
  gemm_k<2,0,false,true><<<48, 256, 0, stream>>>(jE1, jE1, 48);

  for (int t=0;t<32;t++){
    u16* xc0cur = (t&1) ? xc0b : xc0a;
    u16* xc0nxt = (t&1) ? xc0a : xc0b;
    u16* xc1cur = (t&1) ? xc1b : xc1a;
    u16* xc1nxt = (t&1) ? xc1a : xc1b;
    if (use_ehb) attnpart_k<true><<<256, 512, 0, stream>>>(qws, wen, pk, ehb, ctxp, ml);
    else         attnpart_k<false><<<256, 512, 0, stream>>>(qws, wen, pk, eh, ctxp, ml);
    ctxred_k<<<64, 384, 0, stream>>>(ctxp, ml, xc0cur, xpre);
    gru0_k<<<24, 256, 0, stream>>>(xc0cur, xc0nxt, xc1cur, wcat0P, whh0nP, emb0b,
                                   bih0, bhh0, outh, t);
    gru1_k<<<24, 256, 0, stream>>>(xc1cur, xc1nxt, xpre, wcat1P, whh1nP,
                                   bih1, bhh1, outst, outh + 24576, t);
    preq_k<<<24, 256, 0, stream>>>(xpre, wprerP, wqP, preemb, outpre, qws, t);
  }
}